// Round 10
// baseline (837.239 us; speedup 1.0000x reference)
//
#include <hip/hip_runtime.h>

#define B_ 32
#define N_ 196
#define D_ 512
#define C_ 500
#define ND_ 51

typedef __attribute__((ext_vector_type(8))) short short8_t;
typedef __attribute__((ext_vector_type(4))) unsigned short us4_t;
typedef __attribute__((ext_vector_type(4))) float f32x4;

typedef const __attribute__((address_space(1))) unsigned int* gas_p;
typedef __attribute__((address_space(3))) unsigned int* las_p;
#define GLDS(gp, lp) __builtin_amdgcn_global_load_lds((gas_p)(gp), (las_p)(lp), 16, 0, 0)

__device__ inline unsigned short f2bf(float f) {
    unsigned u = __float_as_uint(f);
    u += 0x7FFFu + ((u >> 16) & 1u);   // RNE
    return (unsigned short)(u >> 16);
}

// ---------------- cross-lane helpers ----------------
// DPP (VALU pipe, no LDS): quad_perm xor1=0xB1, xor2=0x4E; row_ror:8=0x128 (== xor8 in a 16-row).
// ror 1/2/4/8 chain reduces a full 16-row under either rotate convention. xor4/16/32/63 via
// __shfl_xor (ds_bpermute, proven). permlane swap asm stays out (R2 NaN culprit).
template <int CTRL>
__device__ inline float dpp_mov(float x) {
    return __uint_as_float(__builtin_amdgcn_update_dpp(
        __float_as_uint(x), __float_as_uint(x), CTRL, 0xF, 0xF, true));
}
__device__ inline float rsum64(float v) {
    v += dpp_mov<0x121>(v);
    v += dpp_mov<0x122>(v);
    v += dpp_mov<0x124>(v);
    v += dpp_mov<0x128>(v);
    v += __shfl_xor(v, 16);
    v += __shfl_xor(v, 32);
    return v;
}
__device__ inline float rmax64(float v) {
    v = fmaxf(v, dpp_mov<0x121>(v));
    v = fmaxf(v, dpp_mov<0x122>(v));
    v = fmaxf(v, dpp_mov<0x124>(v));
    v = fmaxf(v, dpp_mov<0x128>(v));
    v = fmaxf(v, __shfl_xor(v, 16));
    v = fmaxf(v, __shfl_xor(v, 32));
    return v;
}
template <int S>
__device__ inline float xsh(float y) {
    if constexpr (S == 1) return dpp_mov<0xB1>(y);
    else if constexpr (S == 2) return dpp_mov<0x4E>(y);
    else if constexpr (S == 8) return dpp_mov<0x128>(y);
    else return __shfl_xor(y, S);
}

// ---------------- fused prologue kernels ----------------
// k_ctd: one pass over text f32: dot with mean[c] (-> dots[n*C+c]) + bf16 convert (-> textbf).
__global__ __launch_bounds__(256) void k_ctd(const float* __restrict__ text,
                                             const float* __restrict__ mean,
                                             unsigned short* __restrict__ textbf,
                                             float* __restrict__ dots) {
    const int row = blockIdx.x * 4 + (threadIdx.x >> 6);   // n*C_+c, grid exact 25500/4
    const int lane = threadIdx.x & 63;
    const int n = row / C_;
    const int ccol = row - n * C_;
    const float* tp = text + (size_t)row * 512 + lane * 8;
    const float* mp = mean + (size_t)ccol * 512 + lane * 8;
    const float4 f0 = *(const float4*)tp;
    const float4 f1 = *(const float4*)(tp + 4);
    const float4 m0 = *(const float4*)mp;
    const float4 m1 = *(const float4*)(mp + 4);
    float a = f0.x * m0.x + f0.y * m0.y + f0.z * m0.z + f0.w * m0.w
            + f1.x * m1.x + f1.y * m1.y + f1.z * m1.z + f1.w * m1.w;
    a = rsum64(a);
    const us4_t p0 = {f2bf(f0.x), f2bf(f0.y), f2bf(f0.z), f2bf(f0.w)};
    const us4_t p1 = {f2bf(f1.x), f2bf(f1.y), f2bf(f1.z), f2bf(f1.w)};
    *(us4_t*)&textbf[(size_t)row * 512 + lane * 8] = p0;
    *(us4_t*)&textbf[(size_t)row * 512 + lane * 8 + 4] = p1;
    if (lane == 0) dots[row] = a;
}

// k_vsm: v[n,c] = softmax over n of dots[n,c]; one WAVE per column (wave-parallel reduce).
__global__ __launch_bounds__(64) void k_vsm(const float* __restrict__ dots,
                                            float* __restrict__ vout) {
    const int c = blockIdx.x;
    const int lane = threadIdx.x;
    float xv = (lane < ND_) ? dots[lane * C_ + c] : -INFINITY;
    float mx = rmax64(xv);
    float e = (lane < ND_) ? expf(xv - mx) : 0.f;
    float sum = rsum64(e);
    if (lane < ND_) vout[lane * C_ + c] = e / sum;
}

// k_cls: one pass over localf f32: dots with text[0,0,:] and image[b] + bf16 convert.
__global__ __launch_bounds__(256) void k_cls(const float* __restrict__ image,
                                             const float* __restrict__ localf,
                                             const float* __restrict__ text,
                                             unsigned short* __restrict__ localbf,
                                             float* __restrict__ s_ws,
                                             float* __restrict__ wm_ws) {
    const int row = blockIdx.x * 4 + (threadIdx.x >> 6);   // b*N_+m, grid exact 6272/4
    const int lane = threadIdx.x & 63;
    const int b = row / N_;
    const float* lp = localf + (size_t)row * 512 + lane * 8;
    const float4 l0 = *(const float4*)lp;
    const float4 l1 = *(const float4*)(lp + 4);
    const float* ip = image + b * 512 + lane * 8;
    const float* t0p = text + lane * 8;
    const float4 i0 = *(const float4*)ip, i1 = *(const float4*)(ip + 4);
    const float4 t0 = *(const float4*)t0p, t1 = *(const float4*)(t0p + 4);
    float a = l0.x * t0.x + l0.y * t0.y + l0.z * t0.z + l0.w * t0.w
            + l1.x * t1.x + l1.y * t1.y + l1.z * t1.z + l1.w * t1.w;
    float g = l0.x * i0.x + l0.y * i0.y + l0.z * i0.z + l0.w * i0.w
            + l1.x * i1.x + l1.y * i1.y + l1.z * i1.z + l1.w * i1.w;
    a = rsum64(a);
    g = rsum64(g);
    const us4_t p0 = {f2bf(l0.x), f2bf(l0.y), f2bf(l0.z), f2bf(l0.w)};
    const us4_t p1 = {f2bf(l1.x), f2bf(l1.y), f2bf(l1.z), f2bf(l1.w)};
    *(us4_t*)&localbf[(size_t)row * 512 + lane * 8] = p0;
    *(us4_t*)&localbf[(size_t)row * 512 + lane * 8 + 4] = p1;
    if (lane == 0) { s_ws[row] = a; wm_ws[row] = g; }
}

// ---------------- fallback-path kernels (fp32, proven) ----------------
__global__ __launch_bounds__(256) void k_v(const float* __restrict__ mean,
                                           const float* __restrict__ text,
                                           float* __restrict__ vout) {
    const int c = blockIdx.x;
    const int w = threadIdx.x >> 6, lane = threadIdx.x & 63;
    __shared__ float sc[ND_];
    float md[8];
#pragma unroll
    for (int t = 0; t < 8; ++t) md[t] = mean[c * 512 + lane + 64 * t];
    for (int j = 0; j < 13; ++j) {
        const int n = w + 4 * j;
        if (n < ND_) {
            const float* tp = &text[((size_t)n * C_ + c) * 512];
            float a = 0.f;
#pragma unroll
            for (int t = 0; t < 8; ++t) a += md[t] * tp[lane + 64 * t];
            a = rsum64(a);
            if (lane == 0) sc[n] = a;
        }
    }
    __syncthreads();
    if (w == 0) {
        float xv = (lane < ND_) ? sc[lane] : -INFINITY;
        float mx = rmax64(xv);
        float e = (lane < ND_) ? expf(xv - mx) : 0.f;
        float sum = rsum64(e);
        if (lane < ND_) vout[lane * C_ + c] = e / sum;
    }
}

__global__ __launch_bounds__(256) void k_sw(const float* __restrict__ image,
                                            const float* __restrict__ localf,
                                            const float* __restrict__ text,
                                            float* __restrict__ s_ws,
                                            float* __restrict__ wm_ws) {
    const int b = blockIdx.x;
    const int m0 = blockIdx.y * 28;
    const int w = threadIdx.x >> 6, lane = threadIdx.x & 63;
    float t00[8], img[8];
#pragma unroll
    for (int t = 0; t < 8; ++t) {
        t00[t] = text[lane + 64 * t];
        img[t] = image[b * 512 + lane + 64 * t];
    }
    for (int t7 = 0; t7 < 7; ++t7) {
        const int m = m0 + w * 7 + t7;
        const float* lp = &localf[((size_t)b * N_ + m) * 512];
        float a = 0.f, g = 0.f;
#pragma unroll
        for (int t = 0; t < 8; ++t) {
            const float lv = lp[lane + 64 * t];
            a += t00[t] * lv;
            g += img[t] * lv;
        }
        a = rsum64(a);
        g = rsum64(g);
        if (lane == 0) { s_ws[b * N_ + m] = a; wm_ws[b * N_ + m] = g; }
    }
}

// -------- wg[b,k] = softmax over top-50 (by s) of wm, in rank order --------
__global__ __launch_bounds__(64) void k_sel(const float* __restrict__ s_ws,
                                            const float* __restrict__ wm_ws,
                                            float* __restrict__ wgout) {
    const int b = blockIdx.x;
    const int lane = threadIdx.x;
    const unsigned long long ltmask = (1ull << lane) - 1ull;
    __shared__ float cv[64], cw[64];

    float x[4], p[4];
#pragma unroll
    for (int i = 0; i < 4; ++i) {
        const int m = lane + 64 * i;
        x[i] = (m < N_) ? s_ws[b * N_ + m] : -INFINITY;
        p[i] = (m < N_) ? wm_ws[b * N_ + m] : 0.f;
    }
    float lo = -1.02f, hi = 1.02f;
    int cl = N_;
    for (int it = 0; it < 24; ++it) {
        const float t = 0.5f * (lo + hi);
        int cnum = 0;
#pragma unroll
        for (int i = 0; i < 4; ++i) cnum += __popcll(__ballot(x[i] > t));
        if (cnum >= 50) { lo = t; cl = cnum; if (cnum <= 64) break; }
        else hi = t;
    }
    bool f[4];
    if (cl <= 64) {
#pragma unroll
        for (int i = 0; i < 4; ++i) f[i] = x[i] > lo;
    } else {
        int s1 = 0;
#pragma unroll
        for (int i = 0; i < 4; ++i) s1 += __popcll(__ballot(x[i] > hi));
        const int need = 64 - s1;
        int run = 0;
#pragma unroll
        for (int i = 0; i < 4; ++i) {
            const bool mid = (x[i] > lo) && !(x[i] > hi);
            const unsigned long long bm = __ballot(mid);
            const int pos = run + __popcll(bm & ltmask);
            f[i] = (x[i] > hi) || (mid && pos < need);
            run += __popcll(bm);
        }
    }
    int basep = 0;
#pragma unroll
    for (int i = 0; i < 4; ++i) {
        const unsigned long long bm = __ballot(f[i]);
        const int pos = basep + __popcll(bm & ltmask);
        if (f[i]) { cv[pos] = x[i]; cw[pos] = p[i]; }
        basep += __popcll(bm);
    }
    __builtin_amdgcn_s_waitcnt(0);
    float y = (lane < basep) ? cv[lane] : -INFINITY;
    float z = (lane < basep) ? cw[lane] : 0.f;
#pragma unroll
    for (int k = 2; k <= 64; k <<= 1) {
#pragma unroll
        for (int s2 = k >> 1; s2 > 0; s2 >>= 1) {
            const float py = __shfl_xor(y, s2);
            const float pz = __shfl_xor(z, s2);
            const bool keep_max = ((lane & k) == 0) == ((lane & s2) == 0);
            const bool take = keep_max ? (py > y) : (py < y);
            if (take) { y = py; z = pz; }
        }
    }
    float xv = (lane < 50) ? z : -INFINITY;
    float mx = xv;
#pragma unroll
    for (int off = 32; off; off >>= 1) mx = fmaxf(mx, __shfl_xor(mx, off));
    float e = (lane < 50) ? expf(xv - mx) : 0.f;
    float sum = e;
#pragma unroll
    for (int off = 32; off; off >>= 1) sum += __shfl_xor(sum, off);
    if (lane < 50) wgout[b * 50 + lane] = e / sum;
}

// ------------------------------- main fused kernel (bf16 inputs) -------------------------------
// GEMM = R9/R6 proven (593 µs). Top-k REPLACED: no bisect/ballot-compact; instead bitonic
// merge-prune — sort the 4 per-lane chunks (21-step network, lockstep), then
// top64(A,B) = max(A, rev(B)) [bitonic] + 6-step merge, twice. Branchless, data-independent,
// no topk LDS writes. Lanes 0..49 of the result = ranks 0..49 descending (same proven
// direction sequence as before, dotted with wgv).
#define BSTEP1(Y, S, UP) { const float q_ = xsh<S>(Y); if ((q_ > Y) == (UP)) Y = q_; }
#define SORT64(Y) \
    BSTEP1(Y, 1, L1 == L0) \
    BSTEP1(Y, 2, L2 == L1) BSTEP1(Y, 1, L2 == L0) \
    BSTEP1(Y, 4, L3 == L2) BSTEP1(Y, 2, L3 == L1) BSTEP1(Y, 1, L3 == L0) \
    BSTEP1(Y, 8, L4 == L3) BSTEP1(Y, 4, L4 == L2) BSTEP1(Y, 2, L4 == L1) BSTEP1(Y, 1, L4 == L0) \
    BSTEP1(Y, 16, L5 == L4) BSTEP1(Y, 8, L5 == L3) BSTEP1(Y, 4, L5 == L2) BSTEP1(Y, 2, L5 == L1) BSTEP1(Y, 1, L5 == L0) \
    BSTEP1(Y, 32, L5) BSTEP1(Y, 16, L4) BSTEP1(Y, 8, L3) BSTEP1(Y, 4, L2) BSTEP1(Y, 2, L1) BSTEP1(Y, 1, L0)
#define BSORT6(Y) \
    BSTEP1(Y, 32, L5) BSTEP1(Y, 16, L4) BSTEP1(Y, 8, L3) BSTEP1(Y, 4, L2) BSTEP1(Y, 2, L1) BSTEP1(Y, 1, L0)
#define MERGE2(A, B) { const float rb_ = __shfl_xor(B, 63); A = fmaxf(A, rb_); }

__global__ __launch_bounds__(512, 6) void k_main(const float* __restrict__ image,
                                                 const float* __restrict__ mean,
                                                 const unsigned short* __restrict__ localbf,
                                                 const unsigned short* __restrict__ textbf,
                                                 const float* __restrict__ vws,
                                                 const float* __restrict__ wgws,
                                                 float* __restrict__ out) {
    const int b = blockIdx.x;
    const int c = blockIdx.y;
    const int tid = threadIdx.x;
    const int w = tid >> 6;          // 0..7
    const int lane = tid & 63;
    const int quad = lane >> 4;
    const int l16 = lane & 15;

    // A tile: 196 rows x 64 shorts at short 0 (25088 B). B tile: 51(->64) rows at short 12544
    // (byte 25088, 6528 B staged). ST: [51][196] f32 = 39984 B. union = 39984 B.
    __shared__ __align__(16) union SU {
        unsigned short stg[ND_ * 196 * 2];   // A at 0, B at short 12544
        float ST[ND_ * 196];                 // stride 196 (49 * f32x4, 16B-aligned rows)
    } u;

    float base_reg = 0.f;
    if (w == 0) {
        float s = 0.f;
#pragma unroll
        for (int t = 0; t < 8; ++t)
            s += image[b * 512 + lane + 64 * t] * mean[c * 512 + lane + 64 * t];
        s = rsum64(s);
        base_reg = s;
    }

    f32x4 acc[2][4];
    const f32x4 zv = {0.f, 0.f, 0.f, 0.f};
#pragma unroll
    for (int i = 0; i < 2; ++i)
#pragma unroll
        for (int j = 0; j < 4; ++j) acc[i][j] = zv;

    const unsigned short* abase = localbf + (size_t)(b * N_) * 512;

    // hoisted fragment bases (byte offsets into u.stg); all tile steps are immediates
    const char* sp = (const char*)u.stg;
    const unsigned fb0 = (unsigned)(l16 * 128 + ((quad ^ (l16 & 7)) * 16));
    const unsigned fb1 = fb0 ^ 64u;
    const unsigned ab0 = fb0 + (unsigned)(w * 2048);
    const unsigned ab1 = fb1 + (unsigned)(w * 2048);

    for (int ks = 0; ks < 8; ++ks) {
        // A: 1568 16B slots over 512 threads
#pragma unroll
        for (int i = 0; i < 4; ++i) {
            const int s = i * 512 + tid;
            if (s < 1568) {
                const int r = s >> 3;
                const int c8 = (s & 7) ^ (r & 7);
                GLDS(abase + (size_t)r * 512 + ks * 64 + c8 * 8, (char*)u.stg + s * 16);
            }
        }
        // B: 408 slots at byte 25088 (single pass of 512 threads)
        {
            const int s = tid;
            if (s < 408) {
                const int r = s >> 3;
                const int c8 = (s & 7) ^ (r & 7);
                GLDS(textbf + (size_t)(r * C_ + c) * 512 + ks * 64 + c8 * 8,
                     (char*)u.stg + 25088 + s * 16);
            }
        }
        __syncthreads();
#pragma unroll
        for (int kc = 0; kc < 2; ++kc) {
            const unsigned bb = kc ? fb1 : fb0;
            const unsigned aa = kc ? ab1 : ab0;
            short8_t bfr[4];
#pragma unroll
            for (int nt = 0; nt < 4; ++nt)
                bfr[nt] = *(const short8_t*)(sp + 25088 + bb + nt * 2048);
#pragma unroll
            for (int mi = 0; mi < 2; ++mi) {
                const int mt = w + 8 * mi;
                if (mt < 13) {
                    const short8_t af = *(const short8_t*)(sp + aa + mi * 16384);
#pragma unroll
                    for (int nt = 0; nt < 4; ++nt)
                        acc[mi][nt] = __builtin_amdgcn_mfma_f32_16x16x32_bf16(af, bfr[nt], acc[mi][nt], 0, 0, 0);
                }
            }
        }
        __syncthreads();
    }

    // S_T[n][m], stride 196 floats — GUARDED to n < ND_ AND m < 196
#pragma unroll
    for (int nt = 0; nt < 4; ++nt) {
        const int n = nt * 16 + l16;
        if (n < ND_) {
#pragma unroll
            for (int mi = 0; mi < 2; ++mi) {
                const int mt = w + 8 * mi;
                if (mt < 12 || (mt == 12 && quad == 0))
                    *(f32x4*)&u.ST[n * 196 + mt * 16 + quad * 4] = acc[mi][nt];
            }
        }
    }
    __syncthreads();

    // -------- per-column sorted top-50 via bitonic merge-prune; wave w owns n ≡ w (mod 8) -----
    const float wgv = (lane < 50) ? wgws[b * 50 + lane] : 0.f;
    float waveacc = 0.f;

    const bool L0 = (lane & 1) == 0, L1 = (lane & 2) == 0, L2 = (lane & 4) == 0,
               L3 = (lane & 8) == 0, L4 = (lane & 16) == 0, L5 = (lane & 32) == 0;

    for (int t = 0; t < 4; ++t) {
        const int n1 = w + 16 * t;
        const int n2 = n1 + 8;
        const bool a2 = (n2 < ND_);
        if (n1 >= ND_) break;
        const float* rowp1 = &u.ST[n1 * 196];
        const float* rowp2 = &u.ST[(a2 ? n2 : n1) * 196];  // alias (reads only) if col2 inactive

        float x1[4], x2[4];
        if (lane < 49) {
            f32x4 v1 = *(const f32x4*)&rowp1[lane * 4];
            f32x4 v2 = *(const f32x4*)&rowp2[lane * 4];
#pragma unroll
            for (int r = 0; r < 4; ++r) { x1[r] = v1[r]; x2[r] = a2 ? v2[r] : -INFINITY; }
        } else {
#pragma unroll
            for (int r = 0; r < 4; ++r) { x1[r] = -INFINITY; x2[r] = -INFINITY; }
        }

        // phase 1: sort each 64-lane chunk descending (8 independent chains, lockstep)
#pragma unroll
        for (int r = 0; r < 4; ++r) { SORT64(x1[r]) SORT64(x2[r]) }

        // phase 2: top-64 of chunk pairs (max-merge is bitonic), then 6-step merge-sort
        MERGE2(x1[0], x1[1]) MERGE2(x1[2], x1[3])
        MERGE2(x2[0], x2[1]) MERGE2(x2[2], x2[3])
        BSORT6(x1[0]) BSORT6(x1[2]) BSORT6(x2[0]) BSORT6(x2[2])

        // phase 3: top-64 of all 196(+pad), final sort -> lanes 0..49 = ranks 0..49 desc
        MERGE2(x1[0], x1[2]) MERGE2(x2[0], x2[2])
        BSORT6(x1[0]) BSORT6(x2[0])

        float part1 = (lane < 50) ? x1[0] * wgv : 0.f;
        float part2 = (lane < 50) ? x2[0] * wgv : 0.f;
        part1 = rsum64(part1);
        part2 = rsum64(part2);
        waveacc += vws[n1 * C_ + c] * part1;
        if (a2) waveacc += vws[n2 * C_ + c] * part2;
    }

    // wave partial -> ST[w][0] (row w fully consumed by wave w in its round t=0)
    if (lane == 0) u.ST[w * 196] = waveacc;
    __syncthreads();
    if (tid == 0) {
        float r = base_reg;
#pragma unroll
        for (int i = 0; i < 8; ++i) r += u.ST[i * 196];
        out[b * C_ + c] = r;
    }
}

// --------------- fallback main kernel (fp32 inputs, in-kernel cvt; proven) ---------------
__global__ __launch_bounds__(256) void k_main_fb(const float* __restrict__ image,
                                                 const float* __restrict__ localf,
                                                 const float* __restrict__ text,
                                                 const float* __restrict__ mean,
                                                 const float* __restrict__ vws,
                                                 const float* __restrict__ wgws,
                                                 float* __restrict__ out) {
    const int c = blockIdx.x;
    const int b = blockIdx.y;
    const int tid = threadIdx.x;
    const int w = tid >> 6;
    const int lane = tid & 63;
    const int quad = lane >> 4;
    const int l16 = lane & 15;

    __shared__ __align__(16) union SU {
        struct { unsigned short A[208 * 72]; unsigned short Bm[64 * 72]; } st;
        float S[208 * 65];
    } u;
    __shared__ float wavepart[4];
    __shared__ float basev;

    if (w == 0) {
        float s = 0.f;
#pragma unroll
        for (int t = 0; t < 8; ++t)
            s += image[b * 512 + lane + 64 * t] * mean[c * 512 + lane + 64 * t];
#pragma unroll
        for (int off = 32; off; off >>= 1) s += __shfl_xor(s, off);
        if (lane == 0) basev = s;
    }

    f32x4 acc[4][4];
    const f32x4 zv = {0.f, 0.f, 0.f, 0.f};
#pragma unroll
    for (int i = 0; i < 4; ++i)
#pragma unroll
        for (int j = 0; j < 4; ++j) acc[i][j] = zv;

    const int lbase = (b * N_) * 512;
    for (int ks = 0; ks < 8; ++ks) {
        const int k0 = ks * 64;
        for (int e = tid; e < 3328; e += 256) {
            const int m = e >> 4, kc4 = e & 15;
            float4 fv = make_float4(0.f, 0.f, 0.f, 0.f);
            if (m < N_) fv = *(const float4*)&localf[lbase + m * 512 + k0 + kc4 * 4];
            us4_t pk = {f2bf(fv.x), f2bf(fv.y), f2bf(fv.z), f2bf(fv.w)};
            *(us4_t*)&u.st.A[m * 72 + kc4 * 4] = pk;
        }
        for (int e = tid; e < 1024; e += 256) {
            const int n = e >> 4, kc4 = e & 15;
            float4 fv = make_float4(0.f, 0.f, 0.f, 0.f);
            if (n < ND_) fv = *(const float4*)&text[((size_t)n * C_ + c) * 512 + k0 + kc4 * 4];
            us4_t pk = {f2bf(fv.x), f2bf(fv.y), f2bf(fv.z), f2bf(fv.w)};
            *(us4_t*)&u.st.Bm[n * 72 + kc4 * 4] = pk;
        }
        __syncthreads();
#pragma unroll
        for (int kc = 0; kc < 2; ++kc) {
            short8_t bfr[4];
#pragma unroll
            for (int nt = 0; nt < 4; ++nt)
                bfr[nt] = *(const short8_t*)&u.st.Bm[(nt * 16 + l16) * 72 + kc * 32 + quad * 8];
#pragma unroll
            for (int mi = 0; mi < 4; ++mi) {
                const int mt = w + 4 * mi;
                if (mt < 13) {
                    short8_t af = *(const short8_t*)&u.st.A[(mt * 16 + l16) * 72 + kc * 32 + quad * 8];
#pragma unroll
                    for (int nt = 0; nt < 4; ++nt)
                        acc[mi][nt] = __builtin_amdgcn_mfma_f32_16x16x32_bf16(af, bfr[nt], acc[mi][nt], 0, 0, 0);
                }
            }
        }
        __syncthreads();
    }

#pragma unroll
    for (int mi = 0; mi < 4; ++mi) {
        const int mt = w + 4 * mi;
        if (mt < 13) {
#pragma unroll
            for (int nt = 0; nt < 4; ++nt)
#pragma unroll
                for (int r = 0; r < 4; ++r)
                    u.S[(mt * 16 + quad * 4 + r) * 65 + nt * 16 + l16] = acc[mi][nt][r];
        }
    }
    __syncthreads();

    const float wgv = (lane < 50) ? wgws[b * 50 + lane] : 0.f;
    float waveacc = 0.f;

    for (int j = 0; j < 13; ++j) {
        const int n = w + 4 * j;
        if (n < ND_) {
            float x[4];
#pragma unroll
            for (int i = 0; i < 4; ++i) {
                const int m = lane + 64 * i;
                x[i] = (m < N_) ? u.S[m * 65 + n] : -INFINITY;
            }
#pragma unroll
            for (int k = 2; k <= 64; k <<= 1) {
#pragma unroll
                for (int s2 = k >> 1; s2 > 0; s2 >>= 1) {
                    const bool up = ((lane & k) == 0) == ((lane & s2) == 0);
#pragma unroll
                    for (int r = 0; r < 4; ++r) {
                        const float p = __shfl_xor(x[r], s2);
                        x[r] = up ? fmaxf(x[r], p) : fminf(x[r], p);
                    }
                }
            }
            float m01 = fmaxf(x[0], __shfl_xor(x[1], 63));
            float m23 = fmaxf(x[2], __shfl_xor(x[3], 63));
#pragma unroll
            for (int s2 = 32; s2 > 0; s2 >>= 1) {
                const bool up = (lane & s2) == 0;
                const float p0 = __shfl_xor(m01, s2);
                const float p1 = __shfl_xor(m23, s2);
                m01 = up ? fmaxf(m01, p0) : fminf(m01, p0);
                m23 = up ? fmaxf(m23, p1) : fminf(m23, p1);
            }
            float y = fmaxf(m01, __shfl_xor(m23, 63));
#pragma unroll
            for (int s2 = 32; s2 > 0; s2 >>= 1) {
                const bool up = (lane & s2) == 0;
                const float p = __shfl_xor(y, s2);
                y = up ? fmaxf(y, p) : fminf(y, p);
            }
            float part = (lane < 50) ? y * wgv : 0.f;
#pragma unroll
            for (int off = 32; off; off >>= 1) part += __shfl_xor(part, off);
            waveacc += vws[n * C_ + c] * part;
        }
    }

    if (lane == 0) wavepart[w] = waveacc;
    __syncthreads();
    if (tid == 0)
        out[b * C_ + c] = basev + wavepart[0] + wavepart[1] + wavepart[2] + wavepart[3];
}

extern "C" void kernel_launch(void* const* d_in, const int* in_sizes, int n_in,
                              void* d_out, int out_size, void* d_ws, size_t ws_size,
                              hipStream_t stream) {
    (void)in_sizes; (void)n_in; (void)out_size;
    const float* image = (const float*)d_in[0];
    const float* localf = (const float*)d_in[1];
    const float* text  = (const float*)d_in[2];
    const float* mean  = (const float*)d_in[3];
    float* out = (float*)d_out;

    float* vws   = (float*)d_ws;            // 25500
    float* wgws  = vws + ND_ * C_;          // 1600
    float* s_ws  = wgws + B_ * 50;          // 6272
    float* wm_ws = s_ws + B_ * N_;          // 6272
    float* dots  = wm_ws + B_ * N_;         // 25500
    const size_t small_bytes = (size_t)(2 * ND_ * C_ + B_ * 50 + 2 * B_ * N_) * 4;
    const size_t bf_bytes = ((size_t)B_ * N_ * D_ + (size_t)ND_ * C_ * D_) * 2;

    if (ws_size >= small_bytes + bf_bytes) {
        unsigned short* localbf = (unsigned short*)(dots + ND_ * C_);
        unsigned short* textbf  = localbf + (size_t)B_ * N_ * D_;
        hipLaunchKernelGGL(k_ctd, dim3(ND_ * C_ / 4), dim3(256), 0, stream,
                           text, mean, textbf, dots);
        hipLaunchKernelGGL(k_vsm, dim3(C_), dim3(64), 0, stream, dots, vws);
        hipLaunchKernelGGL(k_cls, dim3(B_ * N_ / 4), dim3(256), 0, stream,
                           image, localf, text, localbf, s_ws, wm_ws);
        hipLaunchKernelGGL(k_sel, dim3(B_), dim3(64), 0, stream, s_ws, wm_ws, wgws);
        hipLaunchKernelGGL(k_main, dim3(B_, C_), dim3(512), 0, stream,
                           image, mean, localbf, textbf, vws, wgws, out);
    } else {
        hipLaunchKernelGGL(k_v, dim3(C_), dim3(256), 0, stream, mean, text, vws);
        hipLaunchKernelGGL(k_sw, dim3(B_, 7), dim3(256), 0, stream, image, localf, text, s_ws, wm_ws);
        hipLaunchKernelGGL(k_sel, dim3(B_), dim3(64), 0, stream, s_ws, wm_ws, wgws);
        hipLaunchKernelGGL(k_main_fb, dim3(C_, B_), dim3(256), 0, stream,
                           image, localf, text, mean, vws, wgws, out);
    }
}

// Round 11
// 580.589 us; speedup vs baseline: 1.4420x; 1.4420x over previous
//
#include <hip/hip_runtime.h>

#define B_ 32
#define N_ 196
#define D_ 512
#define C_ 500
#define ND_ 51

typedef __attribute__((ext_vector_type(8))) short short8_t;
typedef __attribute__((ext_vector_type(4))) unsigned short us4_t;
typedef __attribute__((ext_vector_type(4))) float f32x4;

typedef const __attribute__((address_space(1))) unsigned int* gas_p;
typedef __attribute__((address_space(3))) unsigned int* las_p;
#define GLDS(gp, lp) __builtin_amdgcn_global_load_lds((gas_p)(gp), (las_p)(lp), 16, 0, 0)

__device__ inline unsigned short f2bf(float f) {
    unsigned u = __float_as_uint(f);
    u += 0x7FFFu + ((u >> 16) & 1u);   // RNE
    return (unsigned short)(u >> 16);
}

// ---------------- cross-lane helpers ----------------
// DPP (VALU pipe, no LDS): quad_perm xor1=0xB1, xor2=0x4E; row_ror:8=0x128 (== xor8 in a 16-row).
// ror 1/2/4/8 chain reduces a full 16-row under either rotate convention. xor4/16/32 via
// __shfl_xor (ds_bpermute, proven). permlane swap asm stays out (R2 NaN culprit).
template <int CTRL>
__device__ inline float dpp_mov(float x) {
    return __uint_as_float(__builtin_amdgcn_update_dpp(
        __float_as_uint(x), __float_as_uint(x), CTRL, 0xF, 0xF, true));
}
__device__ inline float rsum64(float v) {
    v += dpp_mov<0x121>(v);
    v += dpp_mov<0x122>(v);
    v += dpp_mov<0x124>(v);
    v += dpp_mov<0x128>(v);
    v += __shfl_xor(v, 16);
    v += __shfl_xor(v, 32);
    return v;
}
__device__ inline float rmax64(float v) {
    v = fmaxf(v, dpp_mov<0x121>(v));
    v = fmaxf(v, dpp_mov<0x122>(v));
    v = fmaxf(v, dpp_mov<0x124>(v));
    v = fmaxf(v, dpp_mov<0x128>(v));
    v = fmaxf(v, __shfl_xor(v, 16));
    v = fmaxf(v, __shfl_xor(v, 32));
    return v;
}
__device__ inline float rmin64(float v) {
    v = fminf(v, dpp_mov<0x121>(v));
    v = fminf(v, dpp_mov<0x122>(v));
    v = fminf(v, dpp_mov<0x124>(v));
    v = fminf(v, dpp_mov<0x128>(v));
    v = fminf(v, __shfl_xor(v, 16));
    v = fminf(v, __shfl_xor(v, 32));
    return v;
}
template <int S>
__device__ inline float xsh(float y) {
    if constexpr (S == 1) return dpp_mov<0xB1>(y);
    else if constexpr (S == 2) return dpp_mov<0x4E>(y);
    else if constexpr (S == 8) return dpp_mov<0x128>(y);
    else return __shfl_xor(y, S);
}

// ---------------- fused prologue kernels ----------------
// k_ctd: one pass over text f32: dot with mean[c] (-> dots[n*C+c]) + bf16 convert (-> textbf).
__global__ __launch_bounds__(256) void k_ctd(const float* __restrict__ text,
                                             const float* __restrict__ mean,
                                             unsigned short* __restrict__ textbf,
                                             float* __restrict__ dots) {
    const int row = blockIdx.x * 4 + (threadIdx.x >> 6);   // n*C_+c, grid exact 25500/4
    const int lane = threadIdx.x & 63;
    const int n = row / C_;
    const int ccol = row - n * C_;
    const float* tp = text + (size_t)row * 512 + lane * 8;
    const float* mp = mean + (size_t)ccol * 512 + lane * 8;
    const float4 f0 = *(const float4*)tp;
    const float4 f1 = *(const float4*)(tp + 4);
    const float4 m0 = *(const float4*)mp;
    const float4 m1 = *(const float4*)(mp + 4);
    float a = f0.x * m0.x + f0.y * m0.y + f0.z * m0.z + f0.w * m0.w
            + f1.x * m1.x + f1.y * m1.y + f1.z * m1.z + f1.w * m1.w;
    a = rsum64(a);
    const us4_t p0 = {f2bf(f0.x), f2bf(f0.y), f2bf(f0.z), f2bf(f0.w)};
    const us4_t p1 = {f2bf(f1.x), f2bf(f1.y), f2bf(f1.z), f2bf(f1.w)};
    *(us4_t*)&textbf[(size_t)row * 512 + lane * 8] = p0;
    *(us4_t*)&textbf[(size_t)row * 512 + lane * 8 + 4] = p1;
    if (lane == 0) dots[row] = a;
}

// k_vsm: v[n,c] = softmax over n of dots[n,c]; one WAVE per column (wave-parallel reduce).
__global__ __launch_bounds__(64) void k_vsm(const float* __restrict__ dots,
                                            float* __restrict__ vout) {
    const int c = blockIdx.x;
    const int lane = threadIdx.x;
    float xv = (lane < ND_) ? dots[lane * C_ + c] : -INFINITY;
    float mx = rmax64(xv);
    float e = (lane < ND_) ? expf(xv - mx) : 0.f;
    float sum = rsum64(e);
    if (lane < ND_) vout[lane * C_ + c] = e / sum;
}

// k_cls: one pass over localf f32: dots with text[0,0,:] and image[b] + bf16 convert.
__global__ __launch_bounds__(256) void k_cls(const float* __restrict__ image,
                                             const float* __restrict__ localf,
                                             const float* __restrict__ text,
                                             unsigned short* __restrict__ localbf,
                                             float* __restrict__ s_ws,
                                             float* __restrict__ wm_ws) {
    const int row = blockIdx.x * 4 + (threadIdx.x >> 6);   // b*N_+m, grid exact 6272/4
    const int lane = threadIdx.x & 63;
    const int b = row / N_;
    const float* lp = localf + (size_t)row * 512 + lane * 8;
    const float4 l0 = *(const float4*)lp;
    const float4 l1 = *(const float4*)(lp + 4);
    const float* ip = image + b * 512 + lane * 8;
    const float* t0p = text + lane * 8;
    const float4 i0 = *(const float4*)ip, i1 = *(const float4*)(ip + 4);
    const float4 t0 = *(const float4*)t0p, t1 = *(const float4*)(t0p + 4);
    float a = l0.x * t0.x + l0.y * t0.y + l0.z * t0.z + l0.w * t0.w
            + l1.x * t1.x + l1.y * t1.y + l1.z * t1.z + l1.w * t1.w;
    float g = l0.x * i0.x + l0.y * i0.y + l0.z * i0.z + l0.w * i0.w
            + l1.x * i1.x + l1.y * i1.y + l1.z * i1.z + l1.w * i1.w;
    a = rsum64(a);
    g = rsum64(g);
    const us4_t p0 = {f2bf(l0.x), f2bf(l0.y), f2bf(l0.z), f2bf(l0.w)};
    const us4_t p1 = {f2bf(l1.x), f2bf(l1.y), f2bf(l1.z), f2bf(l1.w)};
    *(us4_t*)&localbf[(size_t)row * 512 + lane * 8] = p0;
    *(us4_t*)&localbf[(size_t)row * 512 + lane * 8 + 4] = p1;
    if (lane == 0) { s_ws[row] = a; wm_ws[row] = g; }
}

// ---------------- fallback-path kernels (fp32, proven) ----------------
__global__ __launch_bounds__(256) void k_v(const float* __restrict__ mean,
                                           const float* __restrict__ text,
                                           float* __restrict__ vout) {
    const int c = blockIdx.x;
    const int w = threadIdx.x >> 6, lane = threadIdx.x & 63;
    __shared__ float sc[ND_];
    float md[8];
#pragma unroll
    for (int t = 0; t < 8; ++t) md[t] = mean[c * 512 + lane + 64 * t];
    for (int j = 0; j < 13; ++j) {
        const int n = w + 4 * j;
        if (n < ND_) {
            const float* tp = &text[((size_t)n * C_ + c) * 512];
            float a = 0.f;
#pragma unroll
            for (int t = 0; t < 8; ++t) a += md[t] * tp[lane + 64 * t];
            a = rsum64(a);
            if (lane == 0) sc[n] = a;
        }
    }
    __syncthreads();
    if (w == 0) {
        float xv = (lane < ND_) ? sc[lane] : -INFINITY;
        float mx = rmax64(xv);
        float e = (lane < ND_) ? expf(xv - mx) : 0.f;
        float sum = rsum64(e);
        if (lane < ND_) vout[lane * C_ + c] = e / sum;
    }
}

__global__ __launch_bounds__(256) void k_sw(const float* __restrict__ image,
                                            const float* __restrict__ localf,
                                            const float* __restrict__ text,
                                            float* __restrict__ s_ws,
                                            float* __restrict__ wm_ws) {
    const int b = blockIdx.x;
    const int m0 = blockIdx.y * 28;
    const int w = threadIdx.x >> 6, lane = threadIdx.x & 63;
    float t00[8], img[8];
#pragma unroll
    for (int t = 0; t < 8; ++t) {
        t00[t] = text[lane + 64 * t];
        img[t] = image[b * 512 + lane + 64 * t];
    }
    for (int t7 = 0; t7 < 7; ++t7) {
        const int m = m0 + w * 7 + t7;
        const float* lp = &localf[((size_t)b * N_ + m) * 512];
        float a = 0.f, g = 0.f;
#pragma unroll
        for (int t = 0; t < 8; ++t) {
            const float lv = lp[lane + 64 * t];
            a += t00[t] * lv;
            g += img[t] * lv;
        }
        a = rsum64(a);
        g = rsum64(g);
        if (lane == 0) { s_ws[b * N_ + m] = a; wm_ws[b * N_ + m] = g; }
    }
}

// -------- wg[b,k] = softmax over top-50 (by s) of wm, in rank order --------
__global__ __launch_bounds__(64) void k_sel(const float* __restrict__ s_ws,
                                            const float* __restrict__ wm_ws,
                                            float* __restrict__ wgout) {
    const int b = blockIdx.x;
    const int lane = threadIdx.x;
    const unsigned long long ltmask = (1ull << lane) - 1ull;
    __shared__ float cv[64], cw[64];

    float x[4], p[4];
#pragma unroll
    for (int i = 0; i < 4; ++i) {
        const int m = lane + 64 * i;
        x[i] = (m < N_) ? s_ws[b * N_ + m] : -INFINITY;
        p[i] = (m < N_) ? wm_ws[b * N_ + m] : 0.f;
    }
    float lo = -1.02f, hi = 1.02f;
    int cl = N_;
    for (int it = 0; it < 24; ++it) {
        const float t = 0.5f * (lo + hi);
        int cnum = 0;
#pragma unroll
        for (int i = 0; i < 4; ++i) cnum += __popcll(__ballot(x[i] > t));
        if (cnum >= 50) { lo = t; cl = cnum; if (cnum <= 64) break; }
        else hi = t;
    }
    bool f[4];
    if (cl <= 64) {
#pragma unroll
        for (int i = 0; i < 4; ++i) f[i] = x[i] > lo;
    } else {
        int s1 = 0;
#pragma unroll
        for (int i = 0; i < 4; ++i) s1 += __popcll(__ballot(x[i] > hi));
        const int need = 64 - s1;
        int run = 0;
#pragma unroll
        for (int i = 0; i < 4; ++i) {
            const bool mid = (x[i] > lo) && !(x[i] > hi);
            const unsigned long long bm = __ballot(mid);
            const int pos = run + __popcll(bm & ltmask);
            f[i] = (x[i] > hi) || (mid && pos < need);
            run += __popcll(bm);
        }
    }
    int basep = 0;
#pragma unroll
    for (int i = 0; i < 4; ++i) {
        const unsigned long long bm = __ballot(f[i]);
        const int pos = basep + __popcll(bm & ltmask);
        if (f[i]) { cv[pos] = x[i]; cw[pos] = p[i]; }
        basep += __popcll(bm);
    }
    __builtin_amdgcn_s_waitcnt(0);
    float y = (lane < basep) ? cv[lane] : -INFINITY;
    float z = (lane < basep) ? cw[lane] : 0.f;
#pragma unroll
    for (int k = 2; k <= 64; k <<= 1) {
#pragma unroll
        for (int s2 = k >> 1; s2 > 0; s2 >>= 1) {
            const float py = __shfl_xor(y, s2);
            const float pz = __shfl_xor(z, s2);
            const bool keep_max = ((lane & k) == 0) == ((lane & s2) == 0);
            const bool take = keep_max ? (py > y) : (py < y);
            if (take) { y = py; z = pz; }
        }
    }
    float xv = (lane < 50) ? z : -INFINITY;
    float mx = xv;
#pragma unroll
    for (int off = 32; off; off >>= 1) mx = fmaxf(mx, __shfl_xor(mx, off));
    float e = (lane < 50) ? expf(xv - mx) : 0.f;
    float sum = e;
#pragma unroll
    for (int off = 32; off; off >>= 1) sum += __shfl_xor(sum, off);
    if (lane < 50) wgout[b * 50 + lane] = e / sum;
}

// ------------------------------- main fused kernel (bf16 inputs) -------------------------------
// R9 structure (proven 593 µs; R10 merge-prune reverted — VALU ops ∝ time, bisect path is
// cheapest). New: column mapping split into 3 UNCONDITIONAL dual rounds (t=0..2: n1=w+16t,
// n2=n1+8, all < 48 < 51 — a2 guards deleted from the hot loop) + a true SINGLE-column tail
// (n=48+w, waves 0..2 only, half the ballots/compares/sort) — the old t=3 round ran the full
// dual machinery on a dead aliased column, on the block critical path.
#define BSTEP(S, UP) { \
    const float q1 = xsh<S>(y1); \
    const float q2 = xsh<S>(y2); \
    if ((q1 > y1) == (UP)) y1 = q1; \
    if ((q2 > y2) == (UP)) y2 = q2; }
#define BSTEP1(Y, S, UP) { const float q_ = xsh<S>(Y); if ((q_ > Y) == (UP)) Y = q_; }
#define SORT64(Y) \
    BSTEP1(Y, 1, L1 == L0) \
    BSTEP1(Y, 2, L2 == L1) BSTEP1(Y, 1, L2 == L0) \
    BSTEP1(Y, 4, L3 == L2) BSTEP1(Y, 2, L3 == L1) BSTEP1(Y, 1, L3 == L0) \
    BSTEP1(Y, 8, L4 == L3) BSTEP1(Y, 4, L4 == L2) BSTEP1(Y, 2, L4 == L1) BSTEP1(Y, 1, L4 == L0) \
    BSTEP1(Y, 16, L5 == L4) BSTEP1(Y, 8, L5 == L3) BSTEP1(Y, 4, L5 == L2) BSTEP1(Y, 2, L5 == L1) BSTEP1(Y, 1, L5 == L0) \
    BSTEP1(Y, 32, L5) BSTEP1(Y, 16, L4) BSTEP1(Y, 8, L3) BSTEP1(Y, 4, L2) BSTEP1(Y, 2, L1) BSTEP1(Y, 1, L0)

__global__ __launch_bounds__(512, 6) void k_main(const float* __restrict__ image,
                                                 const float* __restrict__ mean,
                                                 const unsigned short* __restrict__ localbf,
                                                 const unsigned short* __restrict__ textbf,
                                                 const float* __restrict__ vws,
                                                 const float* __restrict__ wgws,
                                                 float* __restrict__ out) {
    const int b = blockIdx.x;
    const int c = blockIdx.y;
    const int tid = threadIdx.x;
    const int w = tid >> 6;          // 0..7
    const int lane = tid & 63;
    const int quad = lane >> 4;
    const int l16 = lane & 15;

    // A tile: 196 rows x 64 shorts at short 0 (25088 B). B tile: 51(->64) rows at short 12544
    // (byte 25088, 6528 B staged). ST: [51][196] f32 = 39984 B. union = 39984 B.
    __shared__ __align__(16) union SU {
        unsigned short stg[ND_ * 196 * 2];   // A at 0, B at short 12544
        float ST[ND_ * 196];                 // stride 196 (49 * f32x4, 16B-aligned rows)
    } u;

    float base_reg = 0.f;
    if (w == 0) {
        float s = 0.f;
#pragma unroll
        for (int t = 0; t < 8; ++t)
            s += image[b * 512 + lane + 64 * t] * mean[c * 512 + lane + 64 * t];
        s = rsum64(s);
        base_reg = s;
    }

    f32x4 acc[2][4];
    const f32x4 zv = {0.f, 0.f, 0.f, 0.f};
#pragma unroll
    for (int i = 0; i < 2; ++i)
#pragma unroll
        for (int j = 0; j < 4; ++j) acc[i][j] = zv;

    const unsigned short* abase = localbf + (size_t)(b * N_) * 512;

    // hoisted fragment bases (byte offsets into u.stg); all tile steps are immediates
    const char* sp = (const char*)u.stg;
    const unsigned fb0 = (unsigned)(l16 * 128 + ((quad ^ (l16 & 7)) * 16));
    const unsigned fb1 = fb0 ^ 64u;
    const unsigned ab0 = fb0 + (unsigned)(w * 2048);
    const unsigned ab1 = fb1 + (unsigned)(w * 2048);

    for (int ks = 0; ks < 8; ++ks) {
        // A: 1568 16B slots over 512 threads
#pragma unroll
        for (int i = 0; i < 4; ++i) {
            const int s = i * 512 + tid;
            if (s < 1568) {
                const int r = s >> 3;
                const int c8 = (s & 7) ^ (r & 7);
                GLDS(abase + (size_t)r * 512 + ks * 64 + c8 * 8, (char*)u.stg + s * 16);
            }
        }
        // B: 408 slots at byte 25088 (single pass of 512 threads)
        {
            const int s = tid;
            if (s < 408) {
                const int r = s >> 3;
                const int c8 = (s & 7) ^ (r & 7);
                GLDS(textbf + (size_t)(r * C_ + c) * 512 + ks * 64 + c8 * 8,
                     (char*)u.stg + 25088 + s * 16);
            }
        }
        __syncthreads();
#pragma unroll
        for (int kc = 0; kc < 2; ++kc) {
            const unsigned bb = kc ? fb1 : fb0;
            const unsigned aa = kc ? ab1 : ab0;
            short8_t bfr[4];
#pragma unroll
            for (int nt = 0; nt < 4; ++nt)
                bfr[nt] = *(const short8_t*)(sp + 25088 + bb + nt * 2048);
#pragma unroll
            for (int mi = 0; mi < 2; ++mi) {
                const int mt = w + 8 * mi;
                if (mt < 13) {
                    const short8_t af = *(const short8_t*)(sp + aa + mi * 16384);
#pragma unroll
                    for (int nt = 0; nt < 4; ++nt)
                        acc[mi][nt] = __builtin_amdgcn_mfma_f32_16x16x32_bf16(af, bfr[nt], acc[mi][nt], 0, 0, 0);
                }
            }
        }
        __syncthreads();
    }

    // S_T[n][m], stride 196 floats — GUARDED to n < ND_ AND m < 196
#pragma unroll
    for (int nt = 0; nt < 4; ++nt) {
        const int n = nt * 16 + l16;
        if (n < ND_) {
#pragma unroll
            for (int mi = 0; mi < 2; ++mi) {
                const int mt = w + 8 * mi;
                if (mt < 12 || (mt == 12 && quad == 0))
                    *(f32x4*)&u.ST[n * 196 + mt * 16 + quad * 4] = acc[mi][nt];
            }
        }
    }
    __syncthreads();

    // -------- per-column top-50; wave w owns n ≡ w (mod 8); 3 dual rounds + single tail -----
    const float wgv = (lane < 50) ? wgws[b * 50 + lane] : 0.f;
    const unsigned long long ltmask = (1ull << lane) - 1ull;
    float waveacc = 0.f;

    const bool L0 = (lane & 1) == 0, L1 = (lane & 2) == 0, L2 = (lane & 4) == 0,
               L3 = (lane & 8) == 0, L4 = (lane & 16) == 0, L5 = (lane & 32) == 0;

    for (int t = 0; t < 3; ++t) {
        const int n1 = w + 16 * t;
        const int n2 = n1 + 8;             // both always < 48 < ND_
        float* rowp1 = &u.ST[n1 * 196];
        float* rowp2 = &u.ST[n2 * 196];

        float x1[4], x2[4];
        float mn1 = INFINITY, mx1 = -INFINITY, mn2 = INFINITY, mx2 = -INFINITY;
        if (lane < 49) {
            f32x4 v1 = *(const f32x4*)&rowp1[lane * 4];
            f32x4 v2 = *(const f32x4*)&rowp2[lane * 4];
#pragma unroll
            for (int r = 0; r < 4; ++r) {
                x1[r] = v1[r];
                x2[r] = v2[r];
                mx1 = fmaxf(mx1, x1[r]); mn1 = fminf(mn1, x1[r]);
                mx2 = fmaxf(mx2, x2[r]); mn2 = fminf(mn2, x2[r]);
            }
        } else {
#pragma unroll
            for (int r = 0; r < 4; ++r) { x1[r] = -INFINITY; x2[r] = -INFINITY; }
        }

        // data-range bisect init: count(>mn)>=195>=50, count(>mx)=0<50
        float hi1 = rmax64(mx1), lo1 = rmin64(mn1);
        float hi2 = rmax64(mx2), lo2 = rmin64(mn2);
        int cl1 = 256, cl2 = 256;
        bool d1 = false, d2 = false;
        for (int it = 0; it < 24 && !(d1 && d2); ++it) {
            const float t1 = 0.5f * (lo1 + hi1);
            const float t2 = 0.5f * (lo2 + hi2);
            int cn1 = 0, cn2 = 0;
#pragma unroll
            for (int i = 0; i < 4; ++i) {
                cn1 += __popcll(__ballot(x1[i] > t1));
                cn2 += __popcll(__ballot(x2[i] > t2));
            }
            if (!d1) { if (cn1 >= 50) { lo1 = t1; cl1 = cn1; d1 = (cn1 <= 64); } else hi1 = t1; }
            if (!d2) { if (cn2 >= 50) { lo2 = t2; cl2 = cn2; d2 = (cn2 <= 64); } else hi2 = t2; }
        }

        bool f1[4], f2[4];
        int cnt1, cnt2;
        if (cl1 <= 64) {
#pragma unroll
            for (int i = 0; i < 4; ++i) f1[i] = x1[i] > lo1;
            cnt1 = cl1;
        } else {
            int s1 = 0;
#pragma unroll
            for (int i = 0; i < 4; ++i) s1 += __popcll(__ballot(x1[i] > hi1));
            const int need = 64 - s1;
            int run = 0;
#pragma unroll
            for (int i = 0; i < 4; ++i) {
                const bool mid = (x1[i] > lo1) && !(x1[i] > hi1);
                const unsigned long long bm = __ballot(mid);
                const int pos = run + __popcll(bm & ltmask);
                f1[i] = (x1[i] > hi1) || (mid && pos < need);
                run += __popcll(bm);
            }
            cnt1 = 64;
        }
        if (cl2 <= 64) {
#pragma unroll
            for (int i = 0; i < 4; ++i) f2[i] = x2[i] > lo2;
            cnt2 = cl2;
        } else {
            int s1 = 0;
#pragma unroll
            for (int i = 0; i < 4; ++i) s1 += __popcll(__ballot(x2[i] > hi2));
            const int need = 64 - s1;
            int run = 0;
#pragma unroll
            for (int i = 0; i < 4; ++i) {
                const bool mid = (x2[i] > lo2) && !(x2[i] > hi2);
                const unsigned long long bm = __ballot(mid);
                const int pos = run + __popcll(bm & ltmask);
                f2[i] = (x2[i] > hi2) || (mid && pos < need);
                run += __popcll(bm);
            }
            cnt2 = 64;
        }

        int bp1 = 0, bp2 = 0;
#pragma unroll
        for (int i = 0; i < 4; ++i) {
            const unsigned long long bm1 = __ballot(f1[i]);
            const unsigned long long bm2 = __ballot(f2[i]);
            const int p1 = bp1 + __popcll(bm1 & ltmask);
            const int p2 = bp2 + __popcll(bm2 & ltmask);
            if (f1[i]) rowp1[p1] = x1[i];
            if (f2[i]) rowp2[p2] = x2[i];
            bp1 += __popcll(bm1);
            bp2 += __popcll(bm2);
        }
        __builtin_amdgcn_s_waitcnt(0);
        float y1 = (lane < cnt1) ? rowp1[lane] : -INFINITY;
        float y2 = (lane < cnt2) ? rowp2[lane] : -INFINITY;

        // bitonic sort 64: xor1/2/8 on the VALU (DPP), xor4/16/32 via ds_bpermute
        BSTEP(1, L1 == L0)
        BSTEP(2, L2 == L1) BSTEP(1, L2 == L0)
        BSTEP(4, L3 == L2) BSTEP(2, L3 == L1) BSTEP(1, L3 == L0)
        BSTEP(8, L4 == L3) BSTEP(4, L4 == L2) BSTEP(2, L4 == L1) BSTEP(1, L4 == L0)
        BSTEP(16, L5 == L4) BSTEP(8, L5 == L3) BSTEP(4, L5 == L2) BSTEP(2, L5 == L1) BSTEP(1, L5 == L0)
        BSTEP(32, L5) BSTEP(16, L4) BSTEP(8, L3) BSTEP(4, L2) BSTEP(2, L1) BSTEP(1, L0)

        float part1 = (lane < 50) ? y1 * wgv : 0.f;
        float part2 = (lane < 50) ? y2 * wgv : 0.f;
        part1 = rsum64(part1);
        part2 = rsum64(part2);
        waveacc += vws[n1 * C_ + c] * part1;
        waveacc += vws[n2 * C_ + c] * part2;
    }

    // -------- single-column tail: n = 48 + w, waves 0..2 only --------
    if (w < 3) {
        const int n1 = 48 + w;
        float* rowp1 = &u.ST[n1 * 196];
        float x1[4];
        float mn1 = INFINITY, mx1 = -INFINITY;
        if (lane < 49) {
            f32x4 v1 = *(const f32x4*)&rowp1[lane * 4];
#pragma unroll
            for (int r = 0; r < 4; ++r) {
                x1[r] = v1[r];
                mx1 = fmaxf(mx1, x1[r]); mn1 = fminf(mn1, x1[r]);
            }
        } else {
#pragma unroll
            for (int r = 0; r < 4; ++r) x1[r] = -INFINITY;
        }

        float hi1 = rmax64(mx1), lo1 = rmin64(mn1);
        int cl1 = 256;
        bool d1 = false;
        for (int it = 0; it < 24 && !d1; ++it) {
            const float t1 = 0.5f * (lo1 + hi1);
            int cn1 = 0;
#pragma unroll
            for (int i = 0; i < 4; ++i) cn1 += __popcll(__ballot(x1[i] > t1));
            if (cn1 >= 50) { lo1 = t1; cl1 = cn1; d1 = (cn1 <= 64); } else hi1 = t1;
        }

        bool f1[4];
        int cnt1;
        if (cl1 <= 64) {
#pragma unroll
            for (int i = 0; i < 4; ++i) f1[i] = x1[i] > lo1;
            cnt1 = cl1;
        } else {
            int s1 = 0;
#pragma unroll
            for (int i = 0; i < 4; ++i) s1 += __popcll(__ballot(x1[i] > hi1));
            const int need = 64 - s1;
            int run = 0;
#pragma unroll
            for (int i = 0; i < 4; ++i) {
                const bool mid = (x1[i] > lo1) && !(x1[i] > hi1);
                const unsigned long long bm = __ballot(mid);
                const int pos = run + __popcll(bm & ltmask);
                f1[i] = (x1[i] > hi1) || (mid && pos < need);
                run += __popcll(bm);
            }
            cnt1 = 64;
        }

        int bp1 = 0;
#pragma unroll
        for (int i = 0; i < 4; ++i) {
            const unsigned long long bm1 = __ballot(f1[i]);
            const int p1 = bp1 + __popcll(bm1 & ltmask);
            if (f1[i]) rowp1[p1] = x1[i];
            bp1 += __popcll(bm1);
        }
        __builtin_amdgcn_s_waitcnt(0);
        float y1 = (lane < cnt1) ? rowp1[lane] : -INFINITY;
        SORT64(y1)

        float part1 = (lane < 50) ? y1 * wgv : 0.f;
        part1 = rsum64(part1);
        waveacc += vws[n1 * C_ + c] * part1;
    }

    // wave partial -> ST[w][0] (row w fully consumed by wave w in its round t=0)
    if (lane == 0) u.ST[w * 196] = waveacc;
    __syncthreads();
    if (tid == 0) {
        float r = base_reg;
#pragma unroll
        for (int i = 0; i < 8; ++i) r += u.ST[i * 196];
        out[b * C_ + c] = r;
    }
}

// --------------- fallback main kernel (fp32 inputs, in-kernel cvt; proven) ---------------
__global__ __launch_bounds__(256) void k_main_fb(const float* __restrict__ image,
                                                 const float* __restrict__ localf,
                                                 const float* __restrict__ text,
                                                 const float* __restrict__ mean,
                                                 const float* __restrict__ vws,
                                                 const float* __restrict__ wgws,
                                                 float* __restrict__ out) {
    const int c = blockIdx.x;
    const int b = blockIdx.y;
    const int tid = threadIdx.x;
    const int w = tid >> 6;
    const int lane = tid & 63;
    const int quad = lane >> 4;
    const int l16 = lane & 15;

    __shared__ __align__(16) union SU {
        struct { unsigned short A[208 * 72]; unsigned short Bm[64 * 72]; } st;
        float S[208 * 65];
    } u;
    __shared__ float wavepart[4];
    __shared__ float basev;

    if (w == 0) {
        float s = 0.f;
#pragma unroll
        for (int t = 0; t < 8; ++t)
            s += image[b * 512 + lane + 64 * t] * mean[c * 512 + lane + 64 * t];
#pragma unroll
        for (int off = 32; off; off >>= 1) s += __shfl_xor(s, off);
        if (lane == 0) basev = s;
    }

    f32x4 acc[4][4];
    const f32x4 zv = {0.f, 0.f, 0.f, 0.f};
#pragma unroll
    for (int i = 0; i < 4; ++i)
#pragma unroll
        for (int j = 0; j < 4; ++j) acc[i][j] = zv;

    const int lbase = (b * N_) * 512;
    for (int ks = 0; ks < 8; ++ks) {
        const int k0 = ks * 64;
        for (int e = tid; e < 3328; e += 256) {
            const int m = e >> 4, kc4 = e & 15;
            float4 fv = make_float4(0.f, 0.f, 0.f, 0.f);
            if (m < N_) fv = *(const float4*)&localf[lbase + m * 512 + k0 + kc4 * 4];
            us4_t pk = {f2bf(fv.x), f2bf(fv.y), f2bf(fv.z), f2bf(fv.w)};
            *(us4_t*)&u.st.A[m * 72 + kc4 * 4] = pk;
        }
        for (int e = tid; e < 1024; e += 256) {
            const int n = e >> 4, kc4 = e & 15;
            float4 fv = make_float4(0.f, 0.f, 0.f, 0.f);
            if (n < ND_) fv = *(const float4*)&text[((size_t)n * C_ + c) * 512 + k0 + kc4 * 4];
            us4_t pk = {f2bf(fv.x), f2bf(fv.y), f2bf(fv.z), f2bf(fv.w)};
            *(us4_t*)&u.st.Bm[n * 72 + kc4 * 4] = pk;
        }
        __syncthreads();
#pragma unroll
        for (int kc = 0; kc < 2; ++kc) {
            short8_t bfr[4];
#pragma unroll
            for (int nt = 0; nt < 4; ++nt)
                bfr[nt] = *(const short8_t*)&u.st.Bm[(nt * 16 + l16) * 72 + kc * 32 + quad * 8];
#pragma unroll
            for (int mi = 0; mi < 4; ++mi) {
                const int mt = w + 4 * mi;
                if (mt < 13) {
                    short8_t af = *(const short8_t*)&u.st.A[(mt * 16 + l16) * 72 + kc * 32 + quad * 8];
#pragma unroll
                    for (int nt = 0; nt < 4; ++nt)
                        acc[mi][nt] = __builtin_amdgcn_mfma_f32_16x16x32_bf16(af, bfr[nt], acc[mi][nt], 0, 0, 0);
                }
            }
        }
        __syncthreads();
    }

#pragma unroll
    for (int mi = 0; mi < 4; ++mi) {
        const int mt = w + 4 * mi;
        if (mt < 13) {
#pragma unroll
            for (int nt = 0; nt < 4; ++nt)
#pragma unroll
                for (int r = 0; r < 4; ++r)
                    u.S[(mt * 16 + quad * 4 + r) * 65 + nt * 16 + l16] = acc[mi][nt][r];
        }
    }
    __syncthreads();

    const float wgv = (lane < 50) ? wgws[b * 50 + lane] : 0.f;
    float waveacc = 0.f;

    for (int j = 0; j < 13; ++j) {
        const int n = w + 4 * j;
        if (n < ND_) {
            float x[4];
#pragma unroll
            for (int i = 0; i < 4; ++i) {
                const int m = lane + 64 * i;
                x[i] = (m < N_) ? u.S[m * 65 + n] : -INFINITY;
            }
#pragma unroll
            for (int k = 2; k <= 64; k <<= 1) {
#pragma unroll
                for (int s2 = k >> 1; s2 > 0; s2 >>= 1) {
                    const bool up = ((lane & k) == 0) == ((lane & s2) == 0);
#pragma unroll
                    for (int r = 0; r < 4; ++r) {
                        const float p = __shfl_xor(x[r], s2);
                        x[r] = up ? fmaxf(x[r], p) : fminf(x[r], p);
                    }
                }
            }
            float m01 = fmaxf(x[0], __shfl_xor(x[1], 63));
            float m23 = fmaxf(x[2], __shfl_xor(x[3], 63));
#pragma unroll
            for (int s2 = 32; s2 > 0; s2 >>= 1) {
                const bool up = (lane & s2) == 0;
                const float p0 = __shfl_xor(m01, s2);
                const float p1 = __shfl_xor(m23, s2);
                m01 = up ? fmaxf(m01, p0) : fminf(m01, p0);
                m23 = up ? fmaxf(m23, p1) : fminf(m23, p1);
            }
            float y = fmaxf(m01, __shfl_xor(m23, 63));
#pragma unroll
            for (int s2 = 32; s2 > 0; s2 >>= 1) {
                const bool up = (lane & s2) == 0;
                const float p = __shfl_xor(y, s2);
                y = up ? fmaxf(y, p) : fminf(y, p);
            }
            float part = (lane < 50) ? y * wgv : 0.f;
#pragma unroll
            for (int off = 32; off; off >>= 1) part += __shfl_xor(part, off);
            waveacc += vws[n * C_ + c] * part;
        }
    }

    if (lane == 0) wavepart[w] = waveacc;
    __syncthreads();
    if (tid == 0)
        out[b * C_ + c] = basev + wavepart[0] + wavepart[1] + wavepart[2] + wavepart[3];
}

extern "C" void kernel_launch(void* const* d_in, const int* in_sizes, int n_in,
                              void* d_out, int out_size, void* d_ws, size_t ws_size,
                              hipStream_t stream) {
    (void)in_sizes; (void)n_in; (void)out_size;
    const float* image = (const float*)d_in[0];
    const float* localf = (const float*)d_in[1];
    const float* text  = (const float*)d_in[2];
    const float* mean  = (const float*)d_in[3];
    float* out = (float*)d_out;

    float* vws   = (float*)d_ws;            // 25500
    float* wgws  = vws + ND_ * C_;          // 1600
    float* s_ws  = wgws + B_ * 50;          // 6272
    float* wm_ws = s_ws + B_ * N_;          // 6272
    float* dots  = wm_ws + B_ * N_;         // 25500
    const size_t small_bytes = (size_t)(2 * ND_ * C_ + B_ * 50 + 2 * B_ * N_) * 4;
    const size_t bf_bytes = ((size_t)B_ * N_ * D_ + (size_t)ND_ * C_ * D_) * 2;

    if (ws_size >= small_bytes + bf_bytes) {
        unsigned short* localbf = (unsigned short*)(dots + ND_ * C_);
        unsigned short* textbf  = localbf + (size_t)B_ * N_ * D_;
        hipLaunchKernelGGL(k_ctd, dim3(ND_ * C_ / 4), dim3(256), 0, stream,
                           text, mean, textbf, dots);
        hipLaunchKernelGGL(k_vsm, dim3(C_), dim3(64), 0, stream, dots, vws);
        hipLaunchKernelGGL(k_cls, dim3(B_ * N_ / 4), dim3(256), 0, stream,
                           image, localf, text, localbf, s_ws, wm_ws);
        hipLaunchKernelGGL(k_sel, dim3(B_), dim3(64), 0, stream, s_ws, wm_ws, wgws);
        hipLaunchKernelGGL(k_main, dim3(B_, C_), dim3(512), 0, stream,
                           image, mean, localbf, textbf, vws, wgws, out);
    } else {
        hipLaunchKernelGGL(k_v, dim3(C_), dim3(256), 0, stream, mean, text, vws);
        hipLaunchKernelGGL(k_sw, dim3(B_, 7), dim3(256), 0, stream, image, localf, text, s_ws, wm_ws);
        hipLaunchKernelGGL(k_sel, dim3(B_), dim3(64), 0, stream, s_ws, wm_ws, wgws);
        hipLaunchKernelGGL(k_main_fb, dim3(C_, B_), dim3(256), 0, stream,
                           image, localf, text, mean, vws, wgws, out);
    }
}